// Round 1
// baseline (463.469 us; speedup 1.0000x reference)
//
#include <hip/hip_runtime.h>

// LIF neuron scan: x [T=16, B=32, C=128, H=32, W=32] fp32 -> spikes same shape.
//   u1   = mem*0.5 + x*0.5
//   spk  = (u1 > 1.0) ? 1 : 0
//   mem' = spk ? 0 : u1
// Sequential only in T; all B*C*H*W positions independent.
// Memory-bound: 268 MB in + 268 MB out => ~85 us floor at 6.3 TB/s.

constexpr int   T_STEPS     = 16;
constexpr float DECAY       = 0.5f;   // 1 - 1/tau, tau=2
constexpr float INPUT_SCALE = 0.5f;   // 1/tau
constexpr float THRESH      = 1.0f;

__global__ __launch_bounds__(256) void lif_scan_kernel(
    const float* __restrict__ x,
    float*       __restrict__ out,
    int n_per_t)                      // elements per time slice (4,194,304)
{
    // Each thread owns 4 consecutive spatial positions (float4 lane).
    const int i = (blockIdx.x * blockDim.x + threadIdx.x) * 4;
    if (i >= n_per_t) return;

    float4 mem = make_float4(0.f, 0.f, 0.f, 0.f);

    #pragma unroll
    for (int t = 0; t < T_STEPS; ++t) {
        const size_t off = (size_t)t * (size_t)n_per_t + (size_t)i;
        const float4 xv = *reinterpret_cast<const float4*>(x + off);

        float4 u, s;
        u.x = mem.x * DECAY + xv.x * INPUT_SCALE;
        u.y = mem.y * DECAY + xv.y * INPUT_SCALE;
        u.z = mem.z * DECAY + xv.z * INPUT_SCALE;
        u.w = mem.w * DECAY + xv.w * INPUT_SCALE;

        s.x = (u.x > THRESH) ? 1.0f : 0.0f;
        s.y = (u.y > THRESH) ? 1.0f : 0.0f;
        s.z = (u.z > THRESH) ? 1.0f : 0.0f;
        s.w = (u.w > THRESH) ? 1.0f : 0.0f;

        mem.x = (u.x > THRESH) ? 0.0f : u.x;
        mem.y = (u.y > THRESH) ? 0.0f : u.y;
        mem.z = (u.z > THRESH) ? 0.0f : u.z;
        mem.w = (u.w > THRESH) ? 0.0f : u.w;

        *reinterpret_cast<float4*>(out + off) = s;
    }
}

extern "C" void kernel_launch(void* const* d_in, const int* in_sizes, int n_in,
                              void* d_out, int out_size, void* d_ws, size_t ws_size,
                              hipStream_t stream) {
    const float* x   = (const float*)d_in[0];
    float*       out = (float*)d_out;

    const int total   = in_sizes[0];          // T * B * C * H * W
    const int n_per_t = total / T_STEPS;      // 4,194,304

    const int threads = 256;
    const int n_vec   = n_per_t / 4;          // one thread per float4
    const int blocks  = (n_vec + threads - 1) / threads;

    lif_scan_kernel<<<blocks, threads, 0, stream>>>(x, out, n_per_t);
}